// Round 9
// baseline (125.751 us; speedup 1.0000x reference)
//
#include <hip/hip_runtime.h>
#include <hip/hip_bf16.h>

#define EE 256
#define HIDD 150
#define HP 160
#define NN 384
#define NB 2
#define NJT 6
#define RPB 4
#define XJS 264   // XJ row stride (halfs): 132 dw = 4 mod 32 bank walk (2-way worst = free)
#define HTS2 168  // Ht row stride (halfs): 84 dw = 20 mod 32, period-8 bank walk

typedef float f32x4 __attribute__((ext_vector_type(4)));
typedef _Float16 half8 __attribute__((ext_vector_type(8)));
typedef _Float16 half4 __attribute__((ext_vector_type(4)));

// Opaque pin: value becomes asm output -> compiler cannot rematerialize the
// originating global load; fragment MUST stay register-resident.
__device__ __forceinline__ void pin(half8& v) { asm volatile("" : "+v"(v)); }

// ---- merged prep: blocks 0..259 pack weights; blocks 260..451 compute U/V/Xh ----
// frag k-convention: index=lane&15, k=(lane>>4)*8+e (within each 32-K step)
__global__ void prep(const float* __restrict__ W1, const float* __restrict__ W2,
                     const float* __restrict__ b2, const float* __restrict__ X,
                     const float* __restrict__ b1,
                     _Float16* __restrict__ w1p, _Float16* __restrict__ w2p,
                     _Float16* __restrict__ Xh, float* __restrict__ U,
                     float* __restrict__ V) {
  __shared__ float xs[RPB][EE];
  int blk = blockIdx.x;
  int tid = threadIdx.x;
  if (blk < 260) {
    int idx = blk * 256 + tid;
    if (idx < 40960) {
      int e = idx & 7, lane = (idx >> 3) & 63, tile = idx >> 9;
      int t = tile % 10, k8 = tile / 10;
      int eg = k8 * 32 + ((lane >> 4) << 3) + e;
      int h = t * 16 + (lane & 15);
      w1p[idx] = (_Float16)((h < HIDD) ? W1[(512 + eg) * HIDD + h] : 0.f);
    }
    int idx2 = idx - 40960;
    if (idx2 >= 0 && idx2 < 25600) {
      int e = idx2 & 7, lane = (idx2 >> 3) & 63, tile = idx2 >> 9;
      int t = tile % 10, k5 = tile / 10;
      int kk = k5 * 32 + ((lane >> 4) << 3) + e;
      int h = t * 16 + (lane & 15);
      float v = 0.f;
      if (h < HIDD) {
        if (kk < HIDD) v = W2[kk * HIDD + h];
        else if (kk == HIDD) v = b2[h];  // b2 folded: h1[.][150] forced to 1.0 in main
      }
      w2p[idx2] = (_Float16)v;
    }
  } else {
    int r0 = (blk - 260) * RPB;
    for (int q = tid; q < RPB * EE; q += 256) {
      float xv = X[r0 * EE + q];
      xs[q >> 8][q & 255] = xv;
      Xh[r0 * EE + q] = (_Float16)xv;
    }
    __syncthreads();
    int h = tid;
    if (h < HP) {
      float u[RPB] = {0, 0, 0, 0}, v[RPB] = {0, 0, 0, 0};
      if (h < HIDD) {
        for (int e = 0; e < EE; e++) {
          float wa = W1[e * HIDD + h];
          float wb = W1[(EE + e) * HIDD + h];
          #pragma unroll
          for (int r = 0; r < RPB; r++) {
            u[r] = fmaf(xs[r][e], wa, u[r]);
            v[r] = fmaf(xs[r][e], wb, v[r]);
          }
        }
        float bb = b1[h];
        #pragma unroll
        for (int r = 0; r < RPB; r++) u[r] += bb;
      }
      #pragma unroll
      for (int r = 0; r < RPB; r++) {
        U[(r0 + r) * HP + h] = u[r];
        V[(r0 + r) * HP + h] = v[r];
      }
    }
  }
}

// ---- main: block = (b, i-pair, j-tile 64); 10 waves; wave w OWNS h-tile t=w ----
// Weights live in REGISTERS (pinned: 8+5 half8 frags/wave). 3 barriers per block.
__global__ __launch_bounds__(640, 2) void pair_main(
    const _Float16* __restrict__ Xh, const float* __restrict__ M,
    const float* __restrict__ W3, const float* __restrict__ b3,
    const float* __restrict__ U, const float* __restrict__ V,
    const _Float16* __restrict__ w1p, const _Float16* __restrict__ w2p,
    float* __restrict__ out) {
  int bx = blockIdx.x;
  int jt = bx % NJT;
  int ig = (bx / NJT) % (NN / 2);
  int b = bx / (NJT * (NN / 2));
  int i0 = ig * 2;

  int tid = threadIdx.x;
  int lane = tid & 63;
  int w = tid >> 6;        // 0..9: owned t-tile (h = w*16 .. w*16+15)
  int hcol = lane & 15;
  int rgrp = lane >> 4;

  __shared__ __align__(16) _Float16 XJ[64 * XJS];       // 33.8 KB, j-tile of Xh
  __shared__ __align__(16) _Float16 Ht[2][64 * HTS2];   // 42 KB, h1 fp16
  __shared__ __align__(16) _Float16 xsl[2 * EE];        // 1 KB, the 2 i-rows
  __shared__ float ms[64];
  float* partials = reinterpret_cast<float*>(&XJ[0]);   // [10][2][64] f32, aliases XJ (dead after GEMM1)

  // ---- resident weight fragments for this wave's t-slice; loads fly under prologue ----
  half8 w1f[8], w2f[5];
  #pragma unroll
  for (int k8 = 0; k8 < 8; k8++)
    w1f[k8] = *reinterpret_cast<const half8*>(w1p + (k8 * 10 + w) * 512 + lane * 8);
  #pragma unroll
  for (int k5 = 0; k5 < 5; k5++)
    w2f[k5] = *reinterpret_cast<const half8*>(w2p + (k5 * 10 + w) * 512 + lane * 8);

  // ---- stage XJ (64 j-rows x 256), xsl, ms ----
  for (int q = tid; q < 64 * 32; q += 640) {
    int r = q >> 5, c = (q & 31) << 3;
    *reinterpret_cast<half8*>(&XJ[r * XJS + c]) =
        *reinterpret_cast<const half8*>(Xh + (size_t)(b * NN + jt * 64 + r) * EE + c);
  }
  if (tid < 64) {
    int r = tid >> 5, c = (tid & 31) << 3;
    *reinterpret_cast<half8*>(&xsl[r * EE + c]) =
        *reinterpret_cast<const half8*>(Xh + (size_t)(b * NN + i0 + r) * EE + c);
    ms[tid] = M[b * NN + jt * 64 + tid];
  }

  // ---- acc init: U[i,h] + V[j,h] (h = w*16 + rgrp*4 + r) ----
  int hb = w * 16 + rgrp * 4;
  f32x4 acc[2][4];
  {
    float4 u0 = *reinterpret_cast<const float4*>(U + (size_t)(b * NN + i0) * HP + hb);
    float4 u1 = *reinterpret_cast<const float4*>(U + (size_t)(b * NN + i0 + 1) * HP + hb);
    #pragma unroll
    for (int jf = 0; jf < 4; jf++) {
      float4 v4 = *reinterpret_cast<const float4*>(
          V + (size_t)(b * NN + jt * 64 + jf * 16 + hcol) * HP + hb);
      acc[0][jf][0] = u0.x + v4.x; acc[0][jf][1] = u0.y + v4.y;
      acc[0][jf][2] = u0.z + v4.z; acc[0][jf][3] = u0.w + v4.w;
      acc[1][jf][0] = u1.x + v4.x; acc[1][jf][1] = u1.y + v4.y;
      acc[1][jf][2] = u1.z + v4.z; acc[1][jf][3] = u1.w + v4.w;
    }
  }

  // pin weight fragments: from here on they are opaque register values
  #pragma unroll
  for (int k8 = 0; k8 < 8; k8++) pin(w1f[k8]);
  #pragma unroll
  for (int k5 = 0; k5 < 5; k5++) pin(w2f[k5]);

  __syncthreads();  // barrier 1: XJ/xsl visible

  // ---- GEMM1: C1^T[h(own t), j] += W1c^T (xi.xj), weights from registers ----
  #pragma unroll
  for (int k8 = 0; k8 < 8; k8++) {
    half8 xi0 = *reinterpret_cast<const half8*>(&xsl[k8 * 32 + rgrp * 8]);
    half8 xi1 = *reinterpret_cast<const half8*>(&xsl[EE + k8 * 32 + rgrp * 8]);
    #pragma unroll
    for (int jf = 0; jf < 4; jf++) {
      half8 xj = *reinterpret_cast<const half8*>(
          &XJ[(jf * 16 + hcol) * XJS + k8 * 32 + rgrp * 8]);
      acc[0][jf] = __builtin_amdgcn_mfma_f32_16x16x32_f16(w1f[k8], xi0 * xj, acc[0][jf], 0, 0, 0);
      acc[1][jf] = __builtin_amdgcn_mfma_f32_16x16x32_f16(w1f[k8], xi1 * xj, acc[1][jf], 0, 0, 0);
    }
  }

  // ---- relu -> fp16 -> Ht[i][j][h]; wave 9/rgrp1 sets h=150 to 1.0 (b2 via W2 k-row) ----
  #pragma unroll
  for (int i = 0; i < 2; i++) {
    #pragma unroll
    for (int jf = 0; jf < 4; jf++) {
      half4 hv;
      hv[0] = (_Float16)fmaxf(acc[i][jf][0], 0.f);
      hv[1] = (_Float16)fmaxf(acc[i][jf][1], 0.f);
      hv[2] = (_Float16)fmaxf(acc[i][jf][2], 0.f);
      hv[3] = (_Float16)fmaxf(acc[i][jf][3], 0.f);
      if (w == 9 && rgrp == 1) hv[2] = (_Float16)1.0f;  // h = 144+4+2 = 150
      *reinterpret_cast<half4*>(&Ht[i][(jf * 16 + hcol) * HTS2 + hb]) = hv;
    }
  }

  __syncthreads();  // barrier 2: Ht complete

  // ---- GEMM2: D2[j, h2(own t)] = Ht x W2, weights from registers ----
  f32x4 acc2[2][4];
  #pragma unroll
  for (int i = 0; i < 2; i++)
    #pragma unroll
    for (int jf = 0; jf < 4; jf++) {
      acc2[i][jf][0] = 0.f; acc2[i][jf][1] = 0.f;
      acc2[i][jf][2] = 0.f; acc2[i][jf][3] = 0.f;
    }
  #pragma unroll
  for (int k5 = 0; k5 < 5; k5++) {
    #pragma unroll
    for (int i = 0; i < 2; i++) {
      #pragma unroll
      for (int jf = 0; jf < 4; jf++) {
        half8 a = *reinterpret_cast<const half8*>(
            &Ht[i][(jf * 16 + hcol) * HTS2 + k5 * 32 + rgrp * 8]);
        acc2[i][jf] = __builtin_amdgcn_mfma_f32_16x16x32_f16(a, w2f[k5], acc2[i][jf], 0, 0, 0);
      }
    }
  }

  // ---- layer 3 partials: sum over own 16 h2 via W3, reduce across hcol lanes ----
  int h2 = w * 16 + hcol;
  float w3 = (h2 < HIDD) ? W3[h2] : 0.f;
  #pragma unroll
  for (int i = 0; i < 2; i++) {
    #pragma unroll
    for (int jf = 0; jf < 4; jf++) {
      float p0 = fmaxf(acc2[i][jf][0], 0.f) * w3;
      float p1 = fmaxf(acc2[i][jf][1], 0.f) * w3;
      float p2 = fmaxf(acc2[i][jf][2], 0.f) * w3;
      float p3 = fmaxf(acc2[i][jf][3], 0.f) * w3;
      #pragma unroll
      for (int mk = 1; mk <= 8; mk <<= 1) {
        p0 += __shfl_xor(p0, mk);
        p1 += __shfl_xor(p1, mk);
        p2 += __shfl_xor(p2, mk);
        p3 += __shfl_xor(p3, mk);
      }
      if (hcol == 0) {
        float4 pv = {p0, p1, p2, p3};
        *reinterpret_cast<float4*>(
            &partials[(w * 2 + i) * 64 + jf * 16 + rgrp * 4]) = pv;
      }
    }
  }

  __syncthreads();  // barrier 3: partials complete

  if (tid < 128) {
    int i = tid >> 6, j = tid & 63;
    float s = 0.f;
    #pragma unroll
    for (int ww = 0; ww < 10; ww++) s += partials[(ww * 2 + i) * 64 + j];
    float o = (M[b * NN + i0 + i] + ms[j] + s + b3[0]) * (1.f / 3.f);
    out[(size_t)(b * NN + i0 + i) * NN + jt * 64 + j] = o;
  }
}

extern "C" void kernel_launch(void* const* d_in, const int* in_sizes, int n_in,
                              void* d_out, int out_size, void* d_ws, size_t ws_size,
                              hipStream_t stream) {
  const float* X  = (const float*)d_in[0];
  const float* M  = (const float*)d_in[1];
  const float* W1 = (const float*)d_in[2];
  const float* b1 = (const float*)d_in[3];
  const float* W2 = (const float*)d_in[4];
  const float* b2 = (const float*)d_in[5];
  const float* W3 = (const float*)d_in[6];
  const float* b3 = (const float*)d_in[7];
  float* out = (float*)d_out;

  float* U  = (float*)d_ws;                        // 768*160 f32
  float* V  = U + NB * NN * HP;                    // 768*160 f32
  _Float16* Xh  = (_Float16*)(V + NB * NN * HP);   // 768*256 f16
  _Float16* w1p = Xh + NB * NN * EE;               // 40960 f16
  _Float16* w2p = w1p + 40960;                     // 25600 f16

  hipLaunchKernelGGL(prep, dim3(452), dim3(256), 0, stream,
                     W1, W2, b2, X, b1, w1p, w2p, Xh, U, V);
  hipLaunchKernelGGL(pair_main, dim3(NB * (NN / 2) * NJT), dim3(640), 0, stream,
                     Xh, M, W3, b3, U, V, w1p, w2p, out);
}

// Round 10
// 96.148 us; speedup vs baseline: 1.3079x; 1.3079x over previous
//
#include <hip/hip_runtime.h>
#include <hip/hip_bf16.h>

#define EE 256
#define HIDD 150
#define HP 160
#define NN 384
#define NB 2
#define NJT 6
#define RPB 4

typedef float f32x4 __attribute__((ext_vector_type(4)));
typedef _Float16 half8 __attribute__((ext_vector_type(8)));
typedef _Float16 half4 __attribute__((ext_vector_type(4)));

__device__ __forceinline__ void gload16(const _Float16* g, _Float16* l) {
  __builtin_amdgcn_global_load_lds(
      (const __attribute__((address_space(1))) unsigned int*)g,
      (__attribute__((address_space(3))) unsigned int*)l, 16, 0, 0);
}

// ---- merged prep: blocks 0..259 pack weights; blocks 260..451 compute U/V/Xh ----
// frag k-convention: index=lane&15, k=(lane>>4)*8+e (within each 32-K step)
__global__ void prep(const float* __restrict__ W1, const float* __restrict__ W2,
                     const float* __restrict__ b2, const float* __restrict__ X,
                     const float* __restrict__ b1,
                     _Float16* __restrict__ w1p, _Float16* __restrict__ w2p,
                     _Float16* __restrict__ Xh, float* __restrict__ U,
                     float* __restrict__ V) {
  __shared__ float xs[RPB][EE];
  int blk = blockIdx.x;
  int tid = threadIdx.x;
  if (blk < 260) {
    int idx = blk * 256 + tid;
    if (idx < 40960) {
      int e = idx & 7, lane = (idx >> 3) & 63, tile = idx >> 9;
      int t = tile % 10, k8 = tile / 10;
      int eg = k8 * 32 + ((lane >> 4) << 3) + e;
      int h = t * 16 + (lane & 15);
      w1p[idx] = (_Float16)((h < HIDD) ? W1[(512 + eg) * HIDD + h] : 0.f);
    }
    int idx2 = idx - 40960;
    if (idx2 >= 0 && idx2 < 25600) {
      int e = idx2 & 7, lane = (idx2 >> 3) & 63, tile = idx2 >> 9;
      int t = tile % 10, k5 = tile / 10;
      int kk = k5 * 32 + ((lane >> 4) << 3) + e;
      int h = t * 16 + (lane & 15);
      float v = 0.f;
      if (h < HIDD) {
        if (kk < HIDD) v = W2[kk * HIDD + h];
        else if (kk == HIDD) v = b2[h];  // b2 folded: h1[.][150] forced to 1.0 in main
      }
      w2p[idx2] = (_Float16)v;
    }
  } else {
    int r0 = (blk - 260) * RPB;
    for (int q = tid; q < RPB * EE; q += 256) {
      float xv = X[r0 * EE + q];
      xs[q >> 8][q & 255] = xv;
      Xh[r0 * EE + q] = (_Float16)xv;
    }
    __syncthreads();
    int h = tid;
    if (h < HP) {
      float u[RPB] = {0, 0, 0, 0}, v[RPB] = {0, 0, 0, 0};
      if (h < HIDD) {
        for (int e = 0; e < EE; e++) {
          float wa = W1[e * HIDD + h];
          float wb = W1[(EE + e) * HIDD + h];
          #pragma unroll
          for (int r = 0; r < RPB; r++) {
            u[r] = fmaf(xs[r][e], wa, u[r]);
            v[r] = fmaf(xs[r][e], wb, v[r]);
          }
        }
        float bb = b1[h];
        #pragma unroll
        for (int r = 0; r < RPB; r++) u[r] += bb;
      }
      #pragma unroll
      for (int r = 0; r < RPB; r++) {
        U[(r0 + r) * HP + h] = u[r];
        V[(r0 + r) * HP + h] = v[r];
      }
    }
  }
}

// ---- main: block = (b, i-pair, j-tile 64); 4 waves; wave w: i = i0+(w>>1), j-half (w&1) ----
// Round-6 streaming structure (1 sync/chunk, double-buffered gload_lds), but h1 stays in
// REGISTERS: C1^T frag layout -> GEMM2 B-frag layout via fixed ds_bpermute permutation.
// No Ht LDS (saves 43KB -> 3 blocks/CU co-residency covers the per-chunk DMA drain).
__global__ __launch_bounds__(256, 3) void pair_main(
    const _Float16* __restrict__ Xh, const float* __restrict__ M,
    const float* __restrict__ W3, const float* __restrict__ b3,
    const float* __restrict__ U, const float* __restrict__ V,
    const _Float16* __restrict__ w1p, const _Float16* __restrict__ w2p,
    float* __restrict__ out) {
  int bx = blockIdx.x;
  int jt = bx % NJT;
  int ig = (bx / NJT) % (NN / 2);
  int b = bx / (NJT * (NN / 2));
  int i0 = ig * 2;

  int tid = threadIdx.x;
  int lane = tid & 63;
  int w = tid >> 6;
  int hcol = lane & 15;
  int rgrp = lane >> 4;
  int il = w >> 1;
  int jh = w & 1;
  int i = i0 + il;

  __shared__ __align__(16) _Float16 wbuf[2][5120];  // 10 t-tiles x 1KB per chunk
  __shared__ __align__(16) _Float16 xs[2][EE];
  __shared__ float Uf[2][HP];
  __shared__ float W3s[HP];
  __shared__ float ms[64];

  auto stage_chunk = [&](int c, int bf) {
    const _Float16* wsrc = (c < 8) ? (w1p + c * 5120) : (w2p + (c - 8) * 5120);
    _Float16* wdst = &wbuf[bf][0];
    gload16(wsrc + w * 512 + lane * 8, wdst + w * 512);
    gload16(wsrc + (4 + w) * 512 + lane * 8, wdst + (4 + w) * 512);
    if (w < 2) gload16(wsrc + (8 + w) * 512 + lane * 8, wdst + (8 + w) * 512);
  };

  stage_chunk(0, 0);  // in flight during prologue

  reinterpret_cast<unsigned*>(&xs[0][0])[tid] =
      reinterpret_cast<const unsigned*>(Xh + (size_t)(b * NN + i0) * EE)[tid];
  for (int q = tid; q < 2 * HP; q += 256)
    (&Uf[0][0])[q] = U[(b * NN + i0) * HP + q];
  if (tid < HP) W3s[tid] = (tid < HIDD) ? W3[tid] : 0.f;
  if (tid < 64) ms[tid] = M[b * NN + jt * 64 + tid];
  __syncthreads();  // LDS staging visible; chunk 0 drained

  // wave's 2 j sub-tiles: rows jt*64 + jh*32 + jf*16 + hcol
  const _Float16* xr0 = Xh + (size_t)(b * NN + jt * 64 + jh * 32 + hcol) * EE;
  const _Float16* xr1 = xr0 + 16 * EE;

  // acc = C1^T[h, j]; init U[i,h] + V[j,h]
  f32x4 acc[2][10];
  #pragma unroll
  for (int t = 0; t < 10; t++) {
    int h0 = t * 16 + rgrp * 4;
    float4 u4 = *reinterpret_cast<const float4*>(&Uf[il][h0]);
    #pragma unroll
    for (int jf = 0; jf < 2; jf++) {
      int jr = b * NN + jt * 64 + jh * 32 + jf * 16 + hcol;
      float4 v4 = *reinterpret_cast<const float4*>(V + jr * HP + h0);
      acc[jf][t][0] = u4.x + v4.x; acc[jf][t][1] = u4.y + v4.y;
      acc[jf][t][2] = u4.z + v4.z; acc[jf][t][3] = u4.w + v4.w;
    }
  }
  half8 xjc0 = *reinterpret_cast<const half8*>(xr0 + rgrp * 8);
  half8 xjc1 = *reinterpret_cast<const half8*>(xr1 + rgrp * 8);

  // ---- GEMM1: C1^T[h,j] += W1c^T (xi.xj), chunks 0..7 ----
  int buf = 0;
  #pragma unroll
  for (int k8 = 0; k8 < 8; k8++) {
    __syncthreads();                 // prev chunk read-done + this chunk landed
    stage_chunk(k8 + 1, buf ^ 1);    // k8=7 stages chunk 8 (w2p k5=0)
    half8 xi_s = *reinterpret_cast<const half8*>(&xs[il][k8 * 32 + rgrp * 8]);
    half8 a0 = xi_s * xjc0;
    half8 a1 = xi_s * xjc1;
    if (k8 < 7) {
      xjc0 = *reinterpret_cast<const half8*>(xr0 + (k8 + 1) * 32 + rgrp * 8);
      xjc1 = *reinterpret_cast<const half8*>(xr1 + (k8 + 1) * 32 + rgrp * 8);
    }
    #pragma unroll
    for (int t = 0; t < 10; t++) {
      half8 bf = *reinterpret_cast<const half8*>(&wbuf[buf][t * 512 + lane * 8]);
      acc[0][t] = __builtin_amdgcn_mfma_f32_16x16x32_f16(bf, a0, acc[0][t], 0, 0, 0);
      acc[1][t] = __builtin_amdgcn_mfma_f32_16x16x32_f16(bf, a1, acc[1][t], 0, 0, 0);
    }
    buf ^= 1;
  }

  // ---- relu -> fp16 h1, kept in registers as dword pairs ----
  // Hd[jf][t] = half4 h1[j=...+hcol][h=t*16+rgrp*4 .. +3] as 2 dwords
  int Hd[2][10][2];
  #pragma unroll
  for (int jf = 0; jf < 2; jf++) {
    #pragma unroll
    for (int t = 0; t < 10; t++) {
      half4 hv;
      hv[0] = (_Float16)fmaxf(acc[jf][t][0], 0.f);
      hv[1] = (_Float16)fmaxf(acc[jf][t][1], 0.f);
      hv[2] = (_Float16)fmaxf(acc[jf][t][2], 0.f);
      hv[3] = (_Float16)fmaxf(acc[jf][t][3], 0.f);
      if (t == 9 && rgrp == 1) hv[2] = (_Float16)1.0f;  // h=150: b2 via W2 k-row
      int2 q = __builtin_bit_cast(int2, hv);
      Hd[jf][t][0] = q.x;
      Hd[jf][t][1] = q.y;
    }
  }

  // ---- GEMM2: D2^T[h2,j] = W2^T x h1^T, chunks 8..12; B-frag built by bpermute ----
  // dest lane (hcol,rgrp) k-slice k5 needs h1[h=k5*32+rgrp*8 .. +7]:
  //   = H[t=2k5+(rgrp>>1)] of src lanes hcol+32*(rgrp&1) (lo half4) and +16 (hi half4)
  f32x4 acc2[2][10];
  #pragma unroll
  for (int jf = 0; jf < 2; jf++)
    #pragma unroll
    for (int t = 0; t < 10; t++) {
      acc2[jf][t][0] = 0.f; acc2[jf][t][1] = 0.f;
      acc2[jf][t][2] = 0.f; acc2[jf][t][3] = 0.f;
    }
  int la = (hcol + ((rgrp & 1) << 5)) << 2;  // byte addr of source lane A
  int lb = la + 64;                          // source lane B = A + 16 lanes
  bool losel = (rgrp < 2);                   // rgrp 0,1 -> t=2k5 ; rgrp 2,3 -> t=2k5+1
  #pragma unroll
  for (int c = 8; c < 13; c++) {
    __syncthreads();
    if (c < 12) stage_chunk(c + 1, buf ^ 1);
    int k5 = c - 8;
    half8 b2f[2];
    #pragma unroll
    for (int jf = 0; jf < 2; jf++) {
      int d0A = __builtin_amdgcn_ds_bpermute(la, Hd[jf][2 * k5][0]);
      int d0B = __builtin_amdgcn_ds_bpermute(la, Hd[jf][2 * k5 + 1][0]);
      int d1A = __builtin_amdgcn_ds_bpermute(la, Hd[jf][2 * k5][1]);
      int d1B = __builtin_amdgcn_ds_bpermute(la, Hd[jf][2 * k5 + 1][1]);
      int d2A = __builtin_amdgcn_ds_bpermute(lb, Hd[jf][2 * k5][0]);
      int d2B = __builtin_amdgcn_ds_bpermute(lb, Hd[jf][2 * k5 + 1][0]);
      int d3A = __builtin_amdgcn_ds_bpermute(lb, Hd[jf][2 * k5][1]);
      int d3B = __builtin_amdgcn_ds_bpermute(lb, Hd[jf][2 * k5 + 1][1]);
      int4 q;
      q.x = losel ? d0A : d0B;
      q.y = losel ? d1A : d1B;
      q.z = losel ? d2A : d2B;
      q.w = losel ? d3A : d3B;
      b2f[jf] = __builtin_bit_cast(half8, q);
    }
    #pragma unroll
    for (int t = 0; t < 10; t++) {
      half8 bf = *reinterpret_cast<const half8*>(&wbuf[buf][t * 512 + lane * 8]);
      acc2[0][t] = __builtin_amdgcn_mfma_f32_16x16x32_f16(bf, b2f[0], acc2[0][t], 0, 0, 0);
      acc2[1][t] = __builtin_amdgcn_mfma_f32_16x16x32_f16(bf, b2f[1], acc2[1][t], 0, 0, 0);
    }
    buf ^= 1;
  }

  // ---- layer 3: s[j] = sum_h2 relu(D2^T[h2,j]) * W3[h2]; reduce across rgrp ----
  float bb3 = b3[0];
  float mi = M[b * NN + i];
  #pragma unroll
  for (int jf = 0; jf < 2; jf++) {
    float p = 0.f;
    #pragma unroll
    for (int t = 0; t < 10; t++) {
      float4 w34 = *reinterpret_cast<const float4*>(&W3s[t * 16 + rgrp * 4]);
      p = fmaf(fmaxf(acc2[jf][t][0], 0.f), w34.x, p);
      p = fmaf(fmaxf(acc2[jf][t][1], 0.f), w34.y, p);
      p = fmaf(fmaxf(acc2[jf][t][2], 0.f), w34.z, p);
      p = fmaf(fmaxf(acc2[jf][t][3], 0.f), w34.w, p);
    }
    p += __shfl_xor(p, 16);
    p += __shfl_xor(p, 32);
    if (lane < 16) {
      int j = jh * 32 + jf * 16 + lane;
      out[(size_t)(b * NN + i) * NN + jt * 64 + j] =
          (mi + ms[j] + p + bb3) * (1.f / 3.f);
    }
  }
}

extern "C" void kernel_launch(void* const* d_in, const int* in_sizes, int n_in,
                              void* d_out, int out_size, void* d_ws, size_t ws_size,
                              hipStream_t stream) {
  const float* X  = (const float*)d_in[0];
  const float* M  = (const float*)d_in[1];
  const float* W1 = (const float*)d_in[2];
  const float* b1 = (const float*)d_in[3];
  const float* W2 = (const float*)d_in[4];
  const float* b2 = (const float*)d_in[5];
  const float* W3 = (const float*)d_in[6];
  const float* b3 = (const float*)d_in[7];
  float* out = (float*)d_out;

  float* U  = (float*)d_ws;                        // 768*160 f32
  float* V  = U + NB * NN * HP;                    // 768*160 f32
  _Float16* Xh  = (_Float16*)(V + NB * NN * HP);   // 768*256 f16
  _Float16* w1p = Xh + NB * NN * EE;               // 40960 f16
  _Float16* w2p = w1p + 40960;                     // 25600 f16

  hipLaunchKernelGGL(prep, dim3(452), dim3(256), 0, stream,
                     W1, W2, b2, X, b1, w1p, w2p, Xh, U, V);
  hipLaunchKernelGGL(pair_main, dim3(NB * (NN / 2) * NJT), dim3(256), 0, stream,
                     Xh, M, W3, b3, U, V, w1p, w2p, out);
}

// Round 11
// 88.609 us; speedup vs baseline: 1.4192x; 1.0851x over previous
//
#include <hip/hip_runtime.h>
#include <hip/hip_bf16.h>

#define EE 256
#define HIDD 150
#define HP 160
#define NN 384
#define NB 2
#define NJT 6
#define RPB 4
#define NTASK 9216   // 2304 (b,i-pair,jt) units x 4 wave-tasks
#define NWORK 2048   // 256 blocks x 8 waves

typedef float f32x4 __attribute__((ext_vector_type(4)));
typedef _Float16 half8 __attribute__((ext_vector_type(8)));
typedef _Float16 half4 __attribute__((ext_vector_type(4)));

__device__ __forceinline__ void gload16(const _Float16* g, _Float16* l) {
  __builtin_amdgcn_global_load_lds(
      (const __attribute__((address_space(1))) unsigned int*)g,
      (__attribute__((address_space(3))) unsigned int*)l, 16, 0, 0);
}

// ---- merged prep: blocks 0..259 pack weights; blocks 260..451 compute U/V/Xh ----
// frag k-convention: index=lane&15, k=(lane>>4)*8+e (within each 32-K step)
// w1p (40960 halfs) and w2p (25600 halfs) are CONTIGUOUS in d_ws -> one 133KB blob.
__global__ void prep(const float* __restrict__ W1, const float* __restrict__ W2,
                     const float* __restrict__ b2, const float* __restrict__ X,
                     const float* __restrict__ b1,
                     _Float16* __restrict__ w1p, _Float16* __restrict__ w2p,
                     _Float16* __restrict__ Xh, float* __restrict__ U,
                     float* __restrict__ V) {
  __shared__ float xs[RPB][EE];
  int blk = blockIdx.x;
  int tid = threadIdx.x;
  if (blk < 260) {
    int idx = blk * 256 + tid;
    if (idx < 40960) {
      int e = idx & 7, lane = (idx >> 3) & 63, tile = idx >> 9;
      int t = tile % 10, k8 = tile / 10;
      int eg = k8 * 32 + ((lane >> 4) << 3) + e;
      int h = t * 16 + (lane & 15);
      w1p[idx] = (_Float16)((h < HIDD) ? W1[(512 + eg) * HIDD + h] : 0.f);
    }
    int idx2 = idx - 40960;
    if (idx2 >= 0 && idx2 < 25600) {
      int e = idx2 & 7, lane = (idx2 >> 3) & 63, tile = idx2 >> 9;
      int t = tile % 10, k5 = tile / 10;
      int kk = k5 * 32 + ((lane >> 4) << 3) + e;
      int h = t * 16 + (lane & 15);
      float v = 0.f;
      if (h < HIDD) {
        if (kk < HIDD) v = W2[kk * HIDD + h];
        else if (kk == HIDD) v = b2[h];  // b2 folded: h1[.][150] forced to 1.0 in main
      }
      w2p[idx2] = (_Float16)v;
    }
  } else {
    int r0 = (blk - 260) * RPB;
    for (int q = tid; q < RPB * EE; q += 256) {
      float xv = X[r0 * EE + q];
      xs[q >> 8][q & 255] = xv;
      Xh[r0 * EE + q] = (_Float16)xv;
    }
    __syncthreads();
    int h = tid;
    if (h < HP) {
      float u[RPB] = {0, 0, 0, 0}, v[RPB] = {0, 0, 0, 0};
      if (h < HIDD) {
        for (int e = 0; e < EE; e++) {
          float wa = W1[e * HIDD + h];
          float wb = W1[(EE + e) * HIDD + h];
          #pragma unroll
          for (int r = 0; r < RPB; r++) {
            u[r] = fmaf(xs[r][e], wa, u[r]);
            v[r] = fmaf(xs[r][e], wb, v[r]);
          }
        }
        float bb = b1[h];
        #pragma unroll
        for (int r = 0; r < RPB; r++) u[r] += bb;
      }
      #pragma unroll
      for (int r = 0; r < RPB; r++) {
        U[(r0 + r) * HP + h] = u[r];
        V[(r0 + r) * HP + h] = v[r];
      }
    }
  }
}

// ---- main: PERSISTENT weights-in-LDS. Grid = 256 blocks x 8 waves (1 block/CU).
// Stage ALL packed weights (133 KB) to LDS once + ONE barrier; then each wave
// independently executes 4-5 wave-tasks (1 i x 32 j, full 3-layer pipeline) with
// ZERO barriers: B-frags via contiguous ds_read_b128, h1 in regs via ds_bpermute.
__global__ __launch_bounds__(512, 2) void pair_main(
    const _Float16* __restrict__ Xh, const float* __restrict__ M,
    const float* __restrict__ W3, const float* __restrict__ b3,
    const float* __restrict__ U, const float* __restrict__ V,
    const _Float16* __restrict__ w1p, const _Float16* __restrict__ w2p,
    float* __restrict__ out) {
  int tid = threadIdx.x;
  int lane = tid & 63;
  int w = tid >> 6;        // 0..7
  int hcol = lane & 15;
  int rgrp = lane >> 4;

  __shared__ __align__(16) _Float16 wbuf[66560];  // w1p(40960) ++ w2p(25600) = 133 KB
  __shared__ float W3s[HP];

  // ---- stage all weights: 130 x 1KB wave-ops (w1p/w2p contiguous in d_ws) ----
  #pragma unroll
  for (int s = 0; s < 16; s++) {
    int off = (s * 8 + w) * 512;
    gload16(w1p + off + lane * 8, &wbuf[off]);
  }
  if (w < 2) {
    int off = (128 + w) * 512;
    gload16(w1p + off + lane * 8, &wbuf[off]);
  }
  if (tid < HP) W3s[tid] = (tid < HIDD) ? W3[tid] : 0.f;
  __syncthreads();  // the ONLY barrier

  float bb3 = b3[0];
  int la = (hcol + ((rgrp & 1) << 5)) << 2;  // bpermute src lane A (byte addr)
  int lb = la + 64;                          // src lane B = A + 16 lanes
  bool losel = (rgrp < 2);

  #pragma unroll 1
  for (int r = 0; r < 5; r++) {
    int tau = (blockIdx.x << 3) + w + r * NWORK;
    if (tau >= NTASK) break;
    // decode task: replicate round-10 (block bxp, wave wp) mapping
    int bxp = tau >> 2, wp = tau & 3;
    int jt = bxp % NJT;
    int ig = (bxp / NJT) % (NN / 2);
    int b = bxp / (NJT * (NN / 2));
    int il = wp >> 1, jh = wp & 1;
    int i = ig * 2 + il;

    const _Float16* xi = Xh + (size_t)(b * NN + i) * EE;
    const _Float16* xr0 = Xh + (size_t)(b * NN + jt * 64 + jh * 32 + hcol) * EE;
    const _Float16* xr1 = xr0 + 16 * EE;

    // acc = C1^T[h, j]; init U[i,h] + V[j,h]  (direct L2 float4 loads)
    f32x4 acc[2][10];
    #pragma unroll
    for (int t = 0; t < 10; t++) {
      int h0 = t * 16 + rgrp * 4;
      float4 u4 = *reinterpret_cast<const float4*>(U + (size_t)(b * NN + i) * HP + h0);
      #pragma unroll
      for (int jf = 0; jf < 2; jf++) {
        int jr = b * NN + jt * 64 + jh * 32 + jf * 16 + hcol;
        float4 v4 = *reinterpret_cast<const float4*>(V + (size_t)jr * HP + h0);
        acc[jf][t][0] = u4.x + v4.x; acc[jf][t][1] = u4.y + v4.y;
        acc[jf][t][2] = u4.z + v4.z; acc[jf][t][3] = u4.w + v4.w;
      }
    }

    // ---- GEMM1: C1^T[h,j] += W1c^T (xi.xj), 8 K-steps, weights from LDS ----
    #pragma unroll
    for (int k8 = 0; k8 < 8; k8++) {
      half8 xi_s = *reinterpret_cast<const half8*>(xi + k8 * 32 + rgrp * 8);
      half8 xj0 = *reinterpret_cast<const half8*>(xr0 + k8 * 32 + rgrp * 8);
      half8 xj1 = *reinterpret_cast<const half8*>(xr1 + k8 * 32 + rgrp * 8);
      half8 a0 = xi_s * xj0;
      half8 a1 = xi_s * xj1;
      #pragma unroll
      for (int t = 0; t < 10; t++) {
        half8 bf = *reinterpret_cast<const half8*>(&wbuf[k8 * 5120 + t * 512 + lane * 8]);
        acc[0][t] = __builtin_amdgcn_mfma_f32_16x16x32_f16(bf, a0, acc[0][t], 0, 0, 0);
        acc[1][t] = __builtin_amdgcn_mfma_f32_16x16x32_f16(bf, a1, acc[1][t], 0, 0, 0);
      }
    }

    // ---- relu -> fp16 h1 kept in registers as dword pairs ----
    int Hd[2][10][2];
    #pragma unroll
    for (int jf = 0; jf < 2; jf++) {
      #pragma unroll
      for (int t = 0; t < 10; t++) {
        half4 hv;
        hv[0] = (_Float16)fmaxf(acc[jf][t][0], 0.f);
        hv[1] = (_Float16)fmaxf(acc[jf][t][1], 0.f);
        hv[2] = (_Float16)fmaxf(acc[jf][t][2], 0.f);
        hv[3] = (_Float16)fmaxf(acc[jf][t][3], 0.f);
        if (t == 9 && rgrp == 1) hv[2] = (_Float16)1.0f;  // h=150: b2 via W2 k-row
        int2 q = __builtin_bit_cast(int2, hv);
        Hd[jf][t][0] = q.x;
        Hd[jf][t][1] = q.y;
      }
    }

    // ---- GEMM2: D2^T[h2,j] = W2^T x h1^T; B-frag built by fixed bpermute ----
    f32x4 acc2[2][10];
    #pragma unroll
    for (int jf = 0; jf < 2; jf++)
      #pragma unroll
      for (int t = 0; t < 10; t++) {
        acc2[jf][t][0] = 0.f; acc2[jf][t][1] = 0.f;
        acc2[jf][t][2] = 0.f; acc2[jf][t][3] = 0.f;
      }
    #pragma unroll
    for (int k5 = 0; k5 < 5; k5++) {
      half8 b2f[2];
      #pragma unroll
      for (int jf = 0; jf < 2; jf++) {
        int d0A = __builtin_amdgcn_ds_bpermute(la, Hd[jf][2 * k5][0]);
        int d0B = __builtin_amdgcn_ds_bpermute(la, Hd[jf][2 * k5 + 1][0]);
        int d1A = __builtin_amdgcn_ds_bpermute(la, Hd[jf][2 * k5][1]);
        int d1B = __builtin_amdgcn_ds_bpermute(la, Hd[jf][2 * k5 + 1][1]);
        int d2A = __builtin_amdgcn_ds_bpermute(lb, Hd[jf][2 * k5][0]);
        int d2B = __builtin_amdgcn_ds_bpermute(lb, Hd[jf][2 * k5 + 1][0]);
        int d3A = __builtin_amdgcn_ds_bpermute(lb, Hd[jf][2 * k5][1]);
        int d3B = __builtin_amdgcn_ds_bpermute(lb, Hd[jf][2 * k5 + 1][1]);
        int4 q;
        q.x = losel ? d0A : d0B;
        q.y = losel ? d1A : d1B;
        q.z = losel ? d2A : d2B;
        q.w = losel ? d3A : d3B;
        b2f[jf] = __builtin_bit_cast(half8, q);
      }
      #pragma unroll
      for (int t = 0; t < 10; t++) {
        half8 bf = *reinterpret_cast<const half8*>(
            &wbuf[40960 + k5 * 5120 + t * 512 + lane * 8]);
        acc2[0][t] = __builtin_amdgcn_mfma_f32_16x16x32_f16(bf, b2f[0], acc2[0][t], 0, 0, 0);
        acc2[1][t] = __builtin_amdgcn_mfma_f32_16x16x32_f16(bf, b2f[1], acc2[1][t], 0, 0, 0);
      }
    }

    // ---- layer 3: s[j] = sum_h2 relu(D2^T[h2,j]) * W3[h2]; reduce across rgrp ----
    float mi = M[b * NN + i];
    #pragma unroll
    for (int jf = 0; jf < 2; jf++) {
      float p = 0.f;
      #pragma unroll
      for (int t = 0; t < 10; t++) {
        float4 w34 = *reinterpret_cast<const float4*>(&W3s[t * 16 + rgrp * 4]);
        p = fmaf(fmaxf(acc2[jf][t][0], 0.f), w34.x, p);
        p = fmaf(fmaxf(acc2[jf][t][1], 0.f), w34.y, p);
        p = fmaf(fmaxf(acc2[jf][t][2], 0.f), w34.z, p);
        p = fmaf(fmaxf(acc2[jf][t][3], 0.f), w34.w, p);
      }
      p += __shfl_xor(p, 16);
      p += __shfl_xor(p, 32);
      if (lane < 16) {
        int j = jh * 32 + jf * 16 + lane;
        float mj = M[b * NN + jt * 64 + j];
        out[(size_t)(b * NN + i) * NN + jt * 64 + j] =
            (mi + mj + p + bb3) * (1.f / 3.f);
      }
    }
  }
}

extern "C" void kernel_launch(void* const* d_in, const int* in_sizes, int n_in,
                              void* d_out, int out_size, void* d_ws, size_t ws_size,
                              hipStream_t stream) {
  const float* X  = (const float*)d_in[0];
  const float* M  = (const float*)d_in[1];
  const float* W1 = (const float*)d_in[2];
  const float* b1 = (const float*)d_in[3];
  const float* W2 = (const float*)d_in[4];
  const float* b2 = (const float*)d_in[5];
  const float* W3 = (const float*)d_in[6];
  const float* b3 = (const float*)d_in[7];
  float* out = (float*)d_out;

  float* U  = (float*)d_ws;                        // 768*160 f32
  float* V  = U + NB * NN * HP;                    // 768*160 f32
  _Float16* Xh  = (_Float16*)(V + NB * NN * HP);   // 768*256 f16
  _Float16* w1p = Xh + NB * NN * EE;               // 40960 f16  (contiguous with w2p)
  _Float16* w2p = w1p + 40960;                     // 25600 f16

  hipLaunchKernelGGL(prep, dim3(452), dim3(256), 0, stream,
                     W1, W2, b2, X, b1, w1p, w2p, Xh, U, V);
  hipLaunchKernelGGL(pair_main, dim3(256), dim3(512), 0, stream,
                     Xh, M, W3, b3, U, V, w1p, w2p, out);
}